// Round 1
// baseline (903.808 us; speedup 1.0000x reference)
//
#include <hip/hip_runtime.h>

#define Bn 32
#define Ln 2048
#define Dn 768
#define Hn 512
#define Mn (Bn*Ln)
#define EPSC 1e-5f

// d_ws float-offset layout
#define OFF_S1   0        // [512]  per-channel masked sum(h)
#define OFF_S2   512      // [512]  per-channel masked sum(h^2)
#define OFF_MEAN 1024     // [512]
#define OFF_ISTD 1536     // [512]
#define OFF_CNT  2048     // [32]   per-batch valid counts (float)
#define OFF_PH   2304     // [32*512] masked sum of relu(BN(h)) per (b,c)
#define ZERO_N   (OFF_PH + Bn*Hn)       // 18688 floats to zero each launch
#define OFF_H_BYTES (128*1024)          // bf16 h buffer: 65536*512*2 = 64 MB

__global__ void zero_kernel(float* __restrict__ p, int n) {
  int i = blockIdx.x * 256 + threadIdx.x;
  if (i < n) p[i] = 0.f;
}

__global__ void count_kernel(const int* __restrict__ mask, float* __restrict__ cnt) {
  __shared__ int red[256];
  int b = blockIdx.x, t = threadIdx.x;
  int s = 0;
#pragma unroll
  for (int i = 0; i < 8; i++) s += mask[b * Ln + i * 256 + t];
  red[t] = s;
  __syncthreads();
  for (int off = 128; off > 0; off >>= 1) {
    if (t < off) red[t] += red[t + off];
    __syncthreads();
  }
  if (t == 0) cnt[b] = (float)red[0];
}

// round-to-nearest-even fp32 -> bf16 (all values finite here)
static __device__ __forceinline__ unsigned short f2bf(float x) {
  unsigned int u = __float_as_uint(x);
  u += 0x7fffu + ((u >> 16) & 1u);
  return (unsigned short)(u >> 16);
}

// GEMM1: h = hidden @ W1 + b1, fused masked BN-stat accumulation, bf16 store.
// 128x128 tile, BK=8, 256 threads, 8x8 microtile. Column map per thread:
// cols {tx*4..tx*4+3} U {64+tx*4..64+tx*4+3}  (keeps LDS B reads 2-way max).
__global__ __launch_bounds__(256) void gemm1_kernel(
    const float* __restrict__ A, const float* __restrict__ W1,
    const float* __restrict__ b1, const int* __restrict__ mask,
    unsigned short* __restrict__ Hout,
    float* __restrict__ gsum, float* __restrict__ gsq)
{
  const int t = threadIdx.x;
  const int bn0 = blockIdx.x * 128;   // 4 blocks over N=512
  const int bm0 = blockIdx.y * 128;   // 512 blocks over M=65536
  __shared__ float As[8][128];        // transposed A tile: As[k][m]
  __shared__ float Bs[8][128];
  __shared__ float csum[128];
  __shared__ float csq[128];

  float acc[8][8];
#pragma unroll
  for (int i = 0; i < 8; i++)
#pragma unroll
    for (int j = 0; j < 8; j++) acc[i][j] = 0.f;

  const int arow = t >> 1;            // 0..127
  const int acol = (t & 1) * 4;       // 0 or 4
  const int brow = t >> 5;            // 0..7
  const int bcol = (t & 31) * 4;      // 0..124
  const int tx = t & 15;
  const int ty = t >> 4;

  const float* Aptr = A + (size_t)(bm0 + arow) * Dn + acol;
  const float* Bptr = W1 + (size_t)brow * Hn + bn0 + bcol;

  for (int k0 = 0; k0 < Dn; k0 += 8) {
    float4 av = *(const float4*)(Aptr + k0);
    float4 bv = *(const float4*)(Bptr + (size_t)k0 * Hn);
    __syncthreads();
    As[acol + 0][arow] = av.x;
    As[acol + 1][arow] = av.y;
    As[acol + 2][arow] = av.z;
    As[acol + 3][arow] = av.w;
    *(float4*)&Bs[brow][bcol] = bv;
    __syncthreads();
#pragma unroll
    for (int kk = 0; kk < 8; kk++) {
      float4 a0 = *(const float4*)&As[kk][ty * 8];
      float4 a1 = *(const float4*)&As[kk][ty * 8 + 4];
      float4 b0 = *(const float4*)&Bs[kk][tx * 4];
      float4 b1v = *(const float4*)&Bs[kk][64 + tx * 4];
      float a[8] = {a0.x, a0.y, a0.z, a0.w, a1.x, a1.y, a1.z, a1.w};
      float bb[8] = {b0.x, b0.y, b0.z, b0.w, b1v.x, b1v.y, b1v.z, b1v.w};
#pragma unroll
      for (int i = 0; i < 8; i++)
#pragma unroll
        for (int j = 0; j < 8; j++)
          acc[i][j] = fmaf(a[i], bb[j], acc[i][j]);
    }
  }

  // ---- epilogue: bias, masked stats, bf16 store ----
  if (t < 128) { csum[t] = 0.f; csq[t] = 0.f; }
  __syncthreads();

  float mk[8];
#pragma unroll
  for (int i = 0; i < 8; i++) mk[i] = (float)mask[bm0 + ty * 8 + i];

#pragma unroll
  for (int j = 0; j < 8; j++) {
    const int c = (j < 4) ? (tx * 4 + j) : (64 + tx * 4 + (j - 4));
    const float bias = b1[bn0 + c];
    float ps = 0.f, pq = 0.f;
#pragma unroll
    for (int i = 0; i < 8; i++) {
      float v = acc[i][j] + bias;
      acc[i][j] = v;
      ps += v * mk[i];
      pq += v * v * mk[i];
    }
    atomicAdd(&csum[c], ps);
    atomicAdd(&csq[c], pq);
  }

#pragma unroll
  for (int i = 0; i < 8; i++) {
    const size_t row = (size_t)(bm0 + ty * 8 + i);
    ushort4 p0, p1;
    p0.x = f2bf(acc[i][0]); p0.y = f2bf(acc[i][1]);
    p0.z = f2bf(acc[i][2]); p0.w = f2bf(acc[i][3]);
    p1.x = f2bf(acc[i][4]); p1.y = f2bf(acc[i][5]);
    p1.z = f2bf(acc[i][6]); p1.w = f2bf(acc[i][7]);
    *(ushort4*)(Hout + row * Hn + bn0 + tx * 4) = p0;
    *(ushort4*)(Hout + row * Hn + bn0 + 64 + tx * 4) = p1;
  }

  __syncthreads();
  if (t < 128) {
    atomicAdd(&gsum[bn0 + t], csum[t]);
    atomicAdd(&gsq[bn0 + t], csq[t]);
  }
}

__global__ void finalize_kernel(float* __restrict__ ws) {
  __shared__ float nv;
  int t = threadIdx.x;  // 512 threads
  if (t == 0) {
    float s = 0.f;
    for (int i = 0; i < Bn; i++) s += ws[OFF_CNT + i];
    nv = fmaxf(s, 1.f);
  }
  __syncthreads();
  float inv = 1.f / nv;
  float m = ws[OFF_S1 + t] * inv;
  float var = ws[OFF_S2 + t] * inv - m * m;
  ws[OFF_MEAN + t] = m;
  ws[OFF_ISTD + t] = rsqrtf(fmaxf(var, 0.f) + EPSC);
}

// BN + ReLU + masked sum over l -> pooled_h[b,c]. Each thread: 2 channels
// (one bf16x2 = 4B coalesced load per row).
__global__ __launch_bounds__(256) void bnpool_kernel(
    const unsigned int* __restrict__ Hbuf, const int* __restrict__ mask,
    const float* __restrict__ ws, const float* __restrict__ gamma,
    const float* __restrict__ beta, float* __restrict__ pooled)
{
  int t = threadIdx.x;
  int lch = blockIdx.y;   // 16 chunks of 128 rows
  int b = blockIdx.z;     // 32
  int c = 2 * t;
  float sc0 = ws[OFF_ISTD + c] * gamma[c];
  float sh0 = beta[c] - ws[OFF_MEAN + c] * sc0;
  float sc1 = ws[OFF_ISTD + c + 1] * gamma[c + 1];
  float sh1 = beta[c + 1] - ws[OFF_MEAN + c + 1] * sc1;
  float acc0 = 0.f, acc1 = 0.f;
  int rowbase = b * Ln + lch * 128;
  for (int l = 0; l < 128; l++) {
    int row = rowbase + l;
    float mk = (float)mask[row];
    unsigned int hv = Hbuf[(size_t)row * 256 + t];
    float v0 = __uint_as_float(hv << 16);
    float v1 = __uint_as_float(hv & 0xffff0000u);
    acc0 += fmaxf(fmaf(v0, sc0, sh0), 0.f) * mk;
    acc1 += fmaxf(fmaf(v1, sc1, sh1), 0.f) * mk;
  }
  atomicAdd(&pooled[b * Hn + c], acc0);
  atomicAdd(&pooled[b * Hn + c + 1], acc1);
}

// pooled = (pooled_h / counts) @ W2 + b2 * (n_b / max(n_b,1))
__global__ __launch_bounds__(256) void final_kernel(
    const float* __restrict__ pooledh, const float* __restrict__ cnt,
    const float* __restrict__ W2, const float* __restrict__ b2,
    float* __restrict__ out)
{
  __shared__ float pr[512];
  int b = blockIdx.x, t = threadIdx.x;
  float nb = cnt[b];
  float inv = 1.f / fmaxf(nb, 1.f);
  pr[t] = pooledh[b * Hn + t] * inv;
  pr[t + 256] = pooledh[b * Hn + 256 + t] * inv;
  __syncthreads();
  float a0 = 0.f, a1 = 0.f;
  for (int i = 0; i < 512; i++) {
    float p = pr[i];
    a0 = fmaf(p, W2[(size_t)i * Hn + t], a0);
    a1 = fmaf(p, W2[(size_t)i * Hn + 256 + t], a1);
  }
  float fac = nb * inv;  // 1 if any valid token in batch b, else 0
  out[b * Hn + t] = a0 + b2[t] * fac;
  out[b * Hn + 256 + t] = a1 + b2[t + 256] * fac;
}

extern "C" void kernel_launch(void* const* d_in, const int* in_sizes, int n_in,
                              void* d_out, int out_size, void* d_ws, size_t ws_size,
                              hipStream_t stream) {
  const float* hidden = (const float*)d_in[0];
  const int*   mask   = (const int*)d_in[1];
  const float* W1     = (const float*)d_in[2];
  const float* b1     = (const float*)d_in[3];
  const float* gamma  = (const float*)d_in[4];
  const float* beta   = (const float*)d_in[5];
  const float* W2     = (const float*)d_in[6];
  const float* b2     = (const float*)d_in[7];
  float* out = (float*)d_out;
  float* ws  = (float*)d_ws;
  unsigned short* Hbuf = (unsigned short*)((char*)d_ws + OFF_H_BYTES);

  zero_kernel<<<(ZERO_N + 255) / 256, 256, 0, stream>>>(ws, ZERO_N);
  count_kernel<<<Bn, 256, 0, stream>>>(mask, ws + OFF_CNT);
  gemm1_kernel<<<dim3(Hn / 128, Mn / 128), 256, 0, stream>>>(
      hidden, W1, b1, mask, Hbuf, ws + OFF_S1, ws + OFF_S2);
  finalize_kernel<<<1, 512, 0, stream>>>(ws);
  bnpool_kernel<<<dim3(1, 16, Bn), 256, 0, stream>>>(
      (const unsigned int*)Hbuf, mask, ws, gamma, beta, ws + OFF_PH);
  final_kernel<<<Bn, 256, 0, stream>>>(ws + OFF_PH, ws + OFF_CNT, W2, b2, out);
}

// Round 2
// 421.677 us; speedup vs baseline: 2.1434x; 2.1434x over previous
//
#include <hip/hip_runtime.h>
#include <hip/hip_bf16.h>

#define Bn 32
#define Ln 2048
#define Dn 768
#define Hn 512
#define Mn (Bn*Ln)
#define EPSC 1e-5f

// ws float-offset layout
#define OFF_S1   0        // [512] masked sum(h)
#define OFF_S2   512      // [512] masked sum(h^2)
#define OFF_SC   1024     // [512] istd*gamma
#define OFF_SH   1536     // [512] beta - mean*sc
#define OFF_CNT  2048     // [32]
#define OFF_PH   2304     // [32*512] pooled relu(BN(h)) sums
#define ZERO_N   (OFF_PH + Bn*Hn)
#define OFF_W1T_BYTES  131072            // bf16 W1^T [512][768] = 786 KB
#define OFF_H_BYTES    1048576           // tiled bf16 h buffer, 64 MB

#define BM 128
#define BN2 256
#define BK 64
#define LDK 72   // padded LDS k-stride (bf16 units); 144 B = 9*16 B -> 2-way banks, 16B-aligned

typedef __attribute__((ext_vector_type(8))) short bf16x8;
typedef __attribute__((ext_vector_type(4))) float f32x4;

static __device__ __forceinline__ unsigned short f2bf(float x) {
  __hip_bfloat16 h = __float2bfloat16(x);
  return *reinterpret_cast<unsigned short*>(&h);
}
static __device__ __forceinline__ float bf2f(unsigned short u) {
  return __uint_as_float(((unsigned int)u) << 16);
}

__global__ void zero_kernel(float* __restrict__ p, int n) {
  int i = blockIdx.x * 256 + threadIdx.x;
  if (i < n) p[i] = 0.f;
}

__global__ void count_kernel(const int* __restrict__ mask, float* __restrict__ cnt) {
  __shared__ int red[256];
  int b = blockIdx.x, t = threadIdx.x;
  int s = 0;
#pragma unroll
  for (int i = 0; i < 8; i++) s += mask[b * Ln + i * 256 + t];
  red[t] = s;
  __syncthreads();
  for (int off = 128; off > 0; off >>= 1) {
    if (t < off) red[t] += red[t + off];
    __syncthreads();
  }
  if (t == 0) cnt[b] = (float)red[0];
}

// W1 [768][512] fp32 -> W1t [512][768] bf16
__global__ __launch_bounds__(256) void transpose_w1(
    const float* __restrict__ W1, unsigned short* __restrict__ W1t) {
  __shared__ float tile[32][33];
  int kx = blockIdx.x * 32;  // 24
  int nx = blockIdx.y * 32;  // 16
  int tx = threadIdx.x & 31, ty = threadIdx.x >> 5;  // 32 x 8
#pragma unroll
  for (int i = 0; i < 32; i += 8)
    tile[ty + i][tx] = W1[(size_t)(kx + ty + i) * Hn + nx + tx];
  __syncthreads();
#pragma unroll
  for (int i = 0; i < 32; i += 8)
    W1t[(size_t)(nx + ty + i) * Dn + kx + tx] = f2bf(tile[tx][ty + i]);
}

// GEMM1: h = A @ W1 + b1 via bf16 MFMA, fused masked BN stats.
// Block 128Mx256N, BK=64, 512 thr = 8 waves of 64x64.
// Hout layout (tiled, matches fragment order):
//   chunk = by*2+bx (32768 elems) | + w*4096 | + (mt*4+nt)*256 | + lane*4 + r
__global__ __launch_bounds__(512, 4) void gemm1_mfma(
    const float* __restrict__ A, const unsigned short* __restrict__ W1t,
    const float* __restrict__ b1, const int* __restrict__ mask,
    unsigned short* __restrict__ Hout,
    float* __restrict__ gsum, float* __restrict__ gsq)
{
  __shared__ unsigned short As[BM * LDK];   // [m][k]
  __shared__ unsigned short Bs[BN2 * LDK];  // [n][k]
  __shared__ float csum[BN2];
  __shared__ float csq[BN2];

  const int t = threadIdx.x;
  const int bx = blockIdx.x;   // N: 0..1
  const int by = blockIdx.y;   // M: 0..511
  const int bm0 = by * BM;
  const int bn0 = bx * BN2;

  const int w = t >> 6;
  const int lane = t & 63;
  const int wm0 = (w >> 2) * 64;
  const int wn0 = (w & 3) * 64;
  const int l15 = lane & 15;
  const int quad = lane >> 4;

  // staging maps
  const int am = t >> 2;           // 0..127
  const int ak = (t & 3) * 16;     // 0/16/32/48
  const int bn = t >> 1;           // 0..255
  const int bk = (t & 1) * 32;     // 0/32

  const float* Ap = A + (size_t)(bm0 + am) * Dn + ak;
  const unsigned short* Bp = W1t + (size_t)(bn0 + bn) * Dn + bk;

  f32x4 acc[4][4];
#pragma unroll
  for (int i = 0; i < 4; i++)
#pragma unroll
    for (int j = 0; j < 4; j++) acc[i][j] = (f32x4){0.f, 0.f, 0.f, 0.f};

  for (int k0 = 0; k0 < Dn; k0 += BK) {
    float4 a0 = *(const float4*)(Ap + k0);
    float4 a1 = *(const float4*)(Ap + k0 + 4);
    float4 a2 = *(const float4*)(Ap + k0 + 8);
    float4 a3 = *(const float4*)(Ap + k0 + 12);
    uint4 bv0 = *(const uint4*)(Bp + k0);
    uint4 bv1 = *(const uint4*)(Bp + k0 + 8);
    uint4 bv2 = *(const uint4*)(Bp + k0 + 16);
    uint4 bv3 = *(const uint4*)(Bp + k0 + 24);
    __syncthreads();
    uint4 p0, p1;
    p0.x = (unsigned int)f2bf(a0.x) | ((unsigned int)f2bf(a0.y) << 16);
    p0.y = (unsigned int)f2bf(a0.z) | ((unsigned int)f2bf(a0.w) << 16);
    p0.z = (unsigned int)f2bf(a1.x) | ((unsigned int)f2bf(a1.y) << 16);
    p0.w = (unsigned int)f2bf(a1.z) | ((unsigned int)f2bf(a1.w) << 16);
    p1.x = (unsigned int)f2bf(a2.x) | ((unsigned int)f2bf(a2.y) << 16);
    p1.y = (unsigned int)f2bf(a2.z) | ((unsigned int)f2bf(a2.w) << 16);
    p1.z = (unsigned int)f2bf(a3.x) | ((unsigned int)f2bf(a3.y) << 16);
    p1.w = (unsigned int)f2bf(a3.z) | ((unsigned int)f2bf(a3.w) << 16);
    *(uint4*)&As[am * LDK + ak] = p0;
    *(uint4*)&As[am * LDK + ak + 8] = p1;
    *(uint4*)&Bs[bn * LDK + bk] = bv0;
    *(uint4*)&Bs[bn * LDK + bk + 8] = bv1;
    *(uint4*)&Bs[bn * LDK + bk + 16] = bv2;
    *(uint4*)&Bs[bn * LDK + bk + 24] = bv3;
    __syncthreads();
#pragma unroll
    for (int s = 0; s < 2; s++) {
      bf16x8 af[4], bf[4];
#pragma unroll
      for (int mt = 0; mt < 4; mt++)
        af[mt] = *(const bf16x8*)&As[(wm0 + mt * 16 + l15) * LDK + s * 32 + quad * 8];
#pragma unroll
      for (int nt = 0; nt < 4; nt++)
        bf[nt] = *(const bf16x8*)&Bs[(wn0 + nt * 16 + l15) * LDK + s * 32 + quad * 8];
#pragma unroll
      for (int mt = 0; mt < 4; mt++)
#pragma unroll
        for (int nt = 0; nt < 4; nt++)
          acc[mt][nt] = __builtin_amdgcn_mfma_f32_16x16x32_bf16(
              af[mt], bf[nt], acc[mt][nt], 0, 0, 0);
    }
  }

  // ---- epilogue: bias, masked stats, tiled bf16 store ----
  if (t < BN2) { csum[t] = 0.f; csq[t] = 0.f; }
  __syncthreads();

  float mk[4][4];
#pragma unroll
  for (int mt = 0; mt < 4; mt++) {
    int4 mv = *(const int4*)(mask + bm0 + wm0 + mt * 16 + quad * 4);
    mk[mt][0] = (float)mv.x; mk[mt][1] = (float)mv.y;
    mk[mt][2] = (float)mv.z; mk[mt][3] = (float)mv.w;
  }

  const size_t cbase = ((size_t)(by * 2 + bx)) * 32768 + (size_t)w * 4096;
#pragma unroll
  for (int nt = 0; nt < 4; nt++) {
    const int nl = wn0 + nt * 16 + l15;
    const float bias = b1[bn0 + nl];
    float ps = 0.f, pq = 0.f;
#pragma unroll
    for (int mt = 0; mt < 4; mt++) {
      ushort4 st;
      float v0 = acc[mt][nt][0] + bias;
      float v1 = acc[mt][nt][1] + bias;
      float v2 = acc[mt][nt][2] + bias;
      float v3 = acc[mt][nt][3] + bias;
      ps += v0 * mk[mt][0] + v1 * mk[mt][1] + v2 * mk[mt][2] + v3 * mk[mt][3];
      pq += v0 * v0 * mk[mt][0] + v1 * v1 * mk[mt][1] +
            v2 * v2 * mk[mt][2] + v3 * v3 * mk[mt][3];
      st.x = f2bf(v0); st.y = f2bf(v1); st.z = f2bf(v2); st.w = f2bf(v3);
      *(ushort4*)&Hout[cbase + (size_t)(mt * 4 + nt) * 256 + lane * 4] = st;
    }
    atomicAdd(&csum[nl], ps);
    atomicAdd(&csq[nl], pq);
  }

  __syncthreads();
  if (t < BN2) {
    atomicAdd(&gsum[bn0 + t], csum[t]);
    atomicAdd(&gsq[bn0 + t], csq[t]);
  }
}

__global__ void finalize_kernel(float* __restrict__ ws,
                                const float* __restrict__ gamma,
                                const float* __restrict__ beta) {
  __shared__ float nv;
  int t = threadIdx.x;  // 512
  if (t == 0) {
    float s = 0.f;
    for (int i = 0; i < Bn; i++) s += ws[OFF_CNT + i];
    nv = fmaxf(s, 1.f);
  }
  __syncthreads();
  float inv = 1.f / nv;
  float m = ws[OFF_S1 + t] * inv;
  float var = ws[OFF_S2 + t] * inv - m * m;
  float istd = rsqrtf(fmaxf(var, 0.f) + EPSC);
  float sc = istd * gamma[t];
  ws[OFF_SC + t] = sc;
  ws[OFF_SH + t] = beta[t] - m * sc;
}

// BN + ReLU + masked pool over the tiled Hout layout. One block per 32768-elem
// chunk (128 m x 256 n). Fully-coalesced ushort4 reads; index decode is bit math.
__global__ __launch_bounds__(256) void bnpool_kernel(
    const unsigned short* __restrict__ Hbuf, const int* __restrict__ mask,
    const float* __restrict__ sc, const float* __restrict__ sh,
    float* __restrict__ pooled)
{
  __shared__ float pool_c[BN2];
  __shared__ float mkf[BM];
  __shared__ float scs[BN2], shs[BN2];
  const int t = threadIdx.x;
  const int chunk = blockIdx.x;       // 0..1023
  const int by = chunk >> 1, bx = chunk & 1;
  const int b = by >> 4;              // 16 M-blocks per batch
  pool_c[t] = 0.f;
  if (t < BM) mkf[t] = (float)mask[by * BM + t];
  scs[t] = sc[bx * BN2 + t];
  shs[t] = sh[bx * BN2 + t];
  __syncthreads();
  const unsigned short* base = Hbuf + (size_t)chunk * 32768;
#pragma unroll 4
  for (int i = 0; i < 32; i++) {
    int o = (i * 256 + t) * 4;
    ushort4 hv = *(const ushort4*)(base + o);
    int lane = (o >> 2) & 63;
    int mtnt = (o >> 8) & 15;
    int w = o >> 12;
    int nl = (w & 3) * 64 + (mtnt & 3) * 16 + (lane & 15);
    int ml = (w >> 2) * 64 + (mtnt >> 2) * 16 + (lane >> 4) * 4;
    float4 mv = *(const float4*)&mkf[ml];
    float scv = scs[nl], shv = shs[nl];
    float s = 0.f;
    s = fmaf(fmaxf(fmaf(bf2f(hv.x), scv, shv), 0.f), mv.x, s);
    s = fmaf(fmaxf(fmaf(bf2f(hv.y), scv, shv), 0.f), mv.y, s);
    s = fmaf(fmaxf(fmaf(bf2f(hv.z), scv, shv), 0.f), mv.z, s);
    s = fmaf(fmaxf(fmaf(bf2f(hv.w), scv, shv), 0.f), mv.w, s);
    atomicAdd(&pool_c[nl], s);
  }
  __syncthreads();
  atomicAdd(&pooled[b * Hn + bx * BN2 + t], pool_c[t]);
}

// out[b][c] = (PH[b]/max(cnt,1)) @ W2[:,c] + b2[c]*(cnt/max(cnt,1))
__global__ __launch_bounds__(128) void final_kernel(
    const float* __restrict__ pooledh, const float* __restrict__ cnt,
    const float* __restrict__ W2, const float* __restrict__ b2,
    float* __restrict__ out)
{
  __shared__ float pr[Hn];
  int b = blockIdx.x >> 2;
  int cc = blockIdx.x & 3;
  int t = threadIdx.x;
  float nb = cnt[b];
  float inv = 1.f / fmaxf(nb, 1.f);
#pragma unroll
  for (int i = 0; i < 4; i++)
    pr[t + i * 128] = pooledh[b * Hn + t + i * 128] * inv;
  __syncthreads();
  int c = cc * 128 + t;
  float a = 0.f;
  for (int i = 0; i < Hn; i++)
    a = fmaf(pr[i], W2[(size_t)i * Hn + c], a);
  out[b * Hn + c] = a + b2[c] * (nb * inv);
}

extern "C" void kernel_launch(void* const* d_in, const int* in_sizes, int n_in,
                              void* d_out, int out_size, void* d_ws, size_t ws_size,
                              hipStream_t stream) {
  const float* hidden = (const float*)d_in[0];
  const int*   mask   = (const int*)d_in[1];
  const float* W1     = (const float*)d_in[2];
  const float* b1     = (const float*)d_in[3];
  const float* gamma  = (const float*)d_in[4];
  const float* beta   = (const float*)d_in[5];
  const float* W2     = (const float*)d_in[6];
  const float* b2     = (const float*)d_in[7];
  float* out = (float*)d_out;
  float* ws  = (float*)d_ws;
  unsigned short* W1t  = (unsigned short*)((char*)d_ws + OFF_W1T_BYTES);
  unsigned short* Hbuf = (unsigned short*)((char*)d_ws + OFF_H_BYTES);

  zero_kernel<<<(ZERO_N + 255) / 256, 256, 0, stream>>>(ws, ZERO_N);
  count_kernel<<<Bn, 256, 0, stream>>>(mask, ws + OFF_CNT);
  transpose_w1<<<dim3(Dn / 32, Hn / 32), 256, 0, stream>>>(W1, W1t);
  gemm1_mfma<<<dim3(Hn / BN2, Mn / BM), 512, 0, stream>>>(
      hidden, W1t, b1, mask, Hbuf, ws + OFF_S1, ws + OFF_S2);
  finalize_kernel<<<1, Hn, 0, stream>>>(ws, gamma, beta);
  bnpool_kernel<<<(Mn / BM) * (Hn / BN2), 256, 0, stream>>>(
      Hbuf, mask, ws + OFF_SC, ws + OFF_SH, ws + OFF_PH);
  final_kernel<<<Bn * 4, 128, 0, stream>>>(ws + OFF_PH, ws + OFF_CNT, W2, b2, out);
}